// Round 3
// baseline (358.564 us; speedup 1.0000x reference)
//
#include <hip/hip_runtime.h>
#include <hip/hip_bf16.h>

// ---------------------------------------------------------------------------
// KroneNet fused kernel v3 for MI355X (gfx950)
// out[i][j] = softmax_j( s_a[i] * t_j[i] )
// Round-2 lesson: 128 regs of live accumulator (both paths in parallel) blew
// the register budget -> 40 MB scratch spill traffic. v3: each wave owns 32
// samples and runs path a then path b SEQUENTIALLY, sharing acc[8][2] (64
// regs); s_a parks in the per-wave LDS exchange slot between phases. Still
// barrier-free in the main loop. W1 LDS layout padded (+1 slot / 8) to break
// the 4-way quad bank conflict.
// ---------------------------------------------------------------------------

#define BTOT 262144
#define NBLK (BTOT / 256)   // 1024 blocks x 256 samples (2 chunks of 128)

typedef __attribute__((ext_vector_type(4))) float floatx4;
typedef __attribute__((ext_vector_type(8))) short bf16x8;
typedef __attribute__((ext_vector_type(4))) int  intx4;

// workspace / LDS layout (bytes)
#define OFF_W2  0          // 2 paths * 4 ksteps * 8 ntiles * 64 lanes * 16B = 65536
#define OFF_W1  65536      // 2 paths * 144 * float4 (128 + 16 pad slots)    = 4608
#define OFF_B2  70144      // 2 paths * 128 * float                          = 1024
#define OFF_W3A 71168      // 128 * float                                    = 512
#define OFF_W3B 71680      // 3 * 128 * float                                = 1536
#define OFF_B3  73216      // {b3a, b3b0, b3b1, b3b2}                        = 16
#define WS_TOTAL 73232     // multiple of 16

static __device__ __forceinline__ short f2bf(float f) {
    __hip_bfloat16 h = __float2bfloat16(f);
    return __builtin_bit_cast(short, h);
}

// pack two fp32 -> one dword of two bf16 (round-half-up), 3 VALU ops
static __device__ __forceinline__ int pack2bf(float lo, float hi) {
    unsigned a = __builtin_bit_cast(unsigned, lo) + 0x8000u;
    unsigned b = __builtin_bit_cast(unsigned, hi) + 0x8000u;
    return (int)__builtin_amdgcn_perm(b, a, 0x07060302u); // {b.hi16, a.hi16}
}

// compile-time-indexed 4-way select (NO dynamic register indexing)
#define SEL4(a0, a1, a2, a3, i) \
    ((i) == 0 ? (a0) : (i) == 1 ? (a1) : (i) == 2 ? (a2) : (a3))

static __device__ __forceinline__ float redcol(float v) {
    v += __shfl_xor(v, 1); v += __shfl_xor(v, 2);
    v += __shfl_xor(v, 4); v += __shfl_xor(v, 8);
    return v;
}

// W1 slot with bank-conflict padding: one extra float4 slot every 8 entries
static __device__ __forceinline__ int w1slot(int k) { return k + (k >> 3); }

// ---------------------------------------------------------------------------
// Pack kernel. W2 into MFMA B-fragment order: lane holds B[k=quad*8+j][n=col]
// for mfma_f32_16x16x32_bf16 (layout verified in rounds 1-2).
// ---------------------------------------------------------------------------
__global__ void pack_kernel(const float* __restrict__ w1a, const float* __restrict__ w1b,
                            const float* __restrict__ b1a, const float* __restrict__ b1b,
                            const float* __restrict__ w2a, const float* __restrict__ w2b,
                            const float* __restrict__ b2a, const float* __restrict__ b2b,
                            const float* __restrict__ w3a, const float* __restrict__ w3b,
                            const float* __restrict__ b3a, const float* __restrict__ b3b,
                            unsigned char* __restrict__ ws) {
    const int b = blockIdx.x;
    const int tid = threadIdx.x;
    const int path = b >> 5;
    const int r = b & 31;
    const int s = r >> 3;
    const int t = r & 7;
    const float* w2 = path ? w2b : w2a;
    unsigned short* pk = (unsigned short*)(ws + OFF_W2 + path * 32768 + ((s * 8 + t) * 64) * 16);
    #pragma unroll
    for (int q = 0; q < 2; ++q) {
        int e = tid * 2 + q;
        int l = e >> 3, j = e & 7;
        int n = t * 16 + (l & 15);
        int k = s * 32 + ((l >> 4) * 8) + j;
        pk[e] = (unsigned short)f2bf(w2[n * 128 + k]);
    }
    if (b == 0) {
        {
            int pth = tid >> 7, k = tid & 127;
            const float* w1 = pth ? w1b : w1a;
            const float* b1 = pth ? b1b : b1a;
            ((float4*)(ws + OFF_W1))[pth * 144 + w1slot(k)] =
                make_float4(w1[2 * k], w1[2 * k + 1], b1[k], 0.f);
            ((float*)(ws + OFF_B2))[tid] = (pth ? b2b : b2a)[k];
        }
        if (tid < 128) ((float*)(ws + OFF_W3A))[tid] = w3a[tid];
        for (int i = tid; i < 384; i += 256) ((float*)(ws + OFF_W3B))[i] = w3b[i];
        if (tid == 0) {
            float* d = (float*)(ws + OFF_B3);
            d[0] = b3a[0]; d[1] = b3b[0]; d[2] = b3b[1]; d[3] = b3b[2];
        }
    }
}

// ---------------------------------------------------------------------------
// Main kernel: 1024 blocks x 256 threads (4 waves). Each wave owns 32 samples
// per chunk (2 chunks of 128 samples per block) and runs path a, then path b,
// then the softmax — all wave-local, zero __syncthreads in the main loop.
// ---------------------------------------------------------------------------
__global__ __launch_bounds__(256, 2)
void krone_main(const float* __restrict__ x, const unsigned char* __restrict__ ws,
                float* __restrict__ out) {
    __shared__ __align__(16) unsigned char smem[WS_TOTAL];
    __shared__ float4 sEx[4][32];   // per-wave: {s_a, t0, t1, t2} per sample

    const int tid = threadIdx.x;
    {
        const float4* src = (const float4*)ws;
        float4* dst = (float4*)smem;
        for (int i = tid; i < WS_TOTAL / 16; i += 256) dst[i] = src[i];
    }
    __syncthreads();

    const int lane = tid & 63;
    const int wave = tid >> 6;
    const int quad = lane >> 4;
    const int col  = lane & 15;

    const float*  W3A = (const float*)(smem + OFF_W3A);
    const float*  W3B = (const float*)(smem + OFF_W3B);
    const float*  B3  = (const float*)(smem + OFF_B3);
    const float2* xA  = (const float2*)x;
    const float2* xB  = xA + BTOT;

    #pragma unroll 1
    for (int c = 0; c < 2; ++c) {
        const int base = blockIdx.x * 256 + c * 128 + wave * 32;

        #pragma unroll
        for (int p = 0; p < 2; ++p) {
            const bf16x8* W2 = (const bf16x8*)(smem + OFF_W2 + p * 32768);
            const float4* W1 = (const float4*)(smem + OFF_W1) + p * 144;
            const float*  B2 = (const float*)(smem + OFF_B2) + p * 128;
            const float2* xp = p ? xB : xA;

            float2 xv[2];
            #pragma unroll
            for (int mt = 0; mt < 2; ++mt)
                xv[mt] = xp[base + mt * 16 + col];

            floatx4 acc[8][2];
            #pragma unroll
            for (int t = 0; t < 8; ++t)
                #pragma unroll
                for (int mt = 0; mt < 2; ++mt)
                    acc[t][mt] = (floatx4){0.f, 0.f, 0.f, 0.f};

            #pragma unroll
            for (int s = 0; s < 4; ++s) {
                // A-fragment on the fly: lane holds A[m=col][k=s*32+quad*8+j]
                intx4 af[2];
                const int bslot = s * 36 + quad * 9;   // padded W1 slot base
                #pragma unroll
                for (int j2 = 0; j2 < 4; ++j2) {
                    float4 c0 = W1[bslot + 2 * j2];
                    float4 c1 = W1[bslot + 2 * j2 + 1];
                    #pragma unroll
                    for (int mt = 0; mt < 2; ++mt) {
                        float h0 = fmaxf(fmaf(xv[mt].x, c0.x, fmaf(xv[mt].y, c0.y, c0.z)), 0.f);
                        float h1 = fmaxf(fmaf(xv[mt].x, c1.x, fmaf(xv[mt].y, c1.y, c1.z)), 0.f);
                        af[mt][j2] = pack2bf(h0, h1);
                    }
                }
                #pragma unroll
                for (int t = 0; t < 8; ++t) {
                    bf16x8 bfr = W2[(s * 8 + t) * 64 + lane];
                    #pragma unroll
                    for (int mt = 0; mt < 2; ++mt)
                        acc[t][mt] = __builtin_amdgcn_mfma_f32_16x16x32_bf16(
                            __builtin_bit_cast(bf16x8, af[mt]), bfr, acc[t][mt], 0, 0, 0);
                }
            }

            // Epilogue. C layout: (t, mt, r) -> sample mt*16+quad*4+r, n=t*16+col.
            if (p == 0) {
                float pa[2][4] = {};
                #pragma unroll
                for (int t = 0; t < 8; ++t) {
                    int n = t * 16 + col;
                    float b2 = B2[n], w3 = W3A[n];
                    #pragma unroll
                    for (int mt = 0; mt < 2; ++mt)
                        #pragma unroll
                        for (int r = 0; r < 4; ++r)
                            pa[mt][r] = fmaf(w3, fmaxf(acc[t][mt][r] + b2, 0.f), pa[mt][r]);
                }
                #pragma unroll
                for (int mt = 0; mt < 2; ++mt)
                    #pragma unroll
                    for (int r = 0; r < 4; ++r)
                        pa[mt][r] = redcol(pa[mt][r]);
                if (col < 4) {
                    float b3a = B3[0];
                    #pragma unroll
                    for (int mt = 0; mt < 2; ++mt) {
                        int sl = mt * 16 + quad * 4 + col;
                        sEx[wave][sl].x =
                            SEL4(pa[mt][0], pa[mt][1], pa[mt][2], pa[mt][3], col) + b3a;
                    }
                }
            } else {
                float pb0[2][4] = {}, pb1[2][4] = {}, pb2[2][4] = {};
                #pragma unroll
                for (int t = 0; t < 8; ++t) {
                    int n = t * 16 + col;
                    float b2 = B2[n];
                    float w30 = W3B[n], w31 = W3B[128 + n], w32 = W3B[256 + n];
                    #pragma unroll
                    for (int mt = 0; mt < 2; ++mt)
                        #pragma unroll
                        for (int r = 0; r < 4; ++r) {
                            float h = fmaxf(acc[t][mt][r] + b2, 0.f);
                            pb0[mt][r] = fmaf(w30, h, pb0[mt][r]);
                            pb1[mt][r] = fmaf(w31, h, pb1[mt][r]);
                            pb2[mt][r] = fmaf(w32, h, pb2[mt][r]);
                        }
                }
                #pragma unroll
                for (int mt = 0; mt < 2; ++mt)
                    #pragma unroll
                    for (int r = 0; r < 4; ++r) {
                        pb0[mt][r] = redcol(pb0[mt][r]);
                        pb1[mt][r] = redcol(pb1[mt][r]);
                        pb2[mt][r] = redcol(pb2[mt][r]);
                    }
                if (col < 4) {
                    float b30 = B3[1], b31 = B3[2], b32 = B3[3];
                    #pragma unroll
                    for (int mt = 0; mt < 2; ++mt) {
                        int sl = mt * 16 + quad * 4 + col;
                        float v0 = SEL4(pb0[mt][0], pb0[mt][1], pb0[mt][2], pb0[mt][3], col) + b30;
                        float v1 = SEL4(pb1[mt][0], pb1[mt][1], pb1[mt][2], pb1[mt][3], col) + b31;
                        float v2 = SEL4(pb2[mt][0], pb2[mt][1], pb2[mt][2], pb2[mt][3], col) + b32;
                        sEx[wave][sl].y = v0;
                        sEx[wave][sl].z = v1;
                        sEx[wave][sl].w = v2;
                    }
                }
            }
        }

        // softmax — same-wave LDS RAW, ordered by lgkmcnt (no barrier)
        if (lane < 32) {
            float4 v = sEx[wave][lane];
            float y0 = v.x * v.y, y1 = v.x * v.z, y2 = v.x * v.w;
            float m = fmaxf(y0, fmaxf(y1, y2));
            float e0 = __expf(y0 - m), e1 = __expf(y1 - m), e2 = __expf(y2 - m);
            float rs = 1.f / (e0 + e1 + e2);
            long o = (long)(base + lane) * 3;
            out[o]     = e0 * rs;
            out[o + 1] = e1 * rs;
            out[o + 2] = e2 * rs;
        }
    }
}

extern "C" void kernel_launch(void* const* d_in, const int* in_sizes, int n_in,
                              void* d_out, int out_size, void* d_ws, size_t ws_size,
                              hipStream_t stream) {
    const float* x   = (const float*)d_in[0];
    const float* w1a = (const float*)d_in[1];
    const float* w1b = (const float*)d_in[2];
    const float* b1a = (const float*)d_in[3];
    const float* b1b = (const float*)d_in[4];
    const float* w2a = (const float*)d_in[5];
    const float* w2b = (const float*)d_in[6];
    const float* b2a = (const float*)d_in[7];
    const float* b2b = (const float*)d_in[8];
    const float* w3a = (const float*)d_in[9];
    const float* w3b = (const float*)d_in[10];
    const float* b3a = (const float*)d_in[11];
    const float* b3b = (const float*)d_in[12];
    unsigned char* ws = (unsigned char*)d_ws;
    float* out = (float*)d_out;

    pack_kernel<<<64, 256, 0, stream>>>(w1a, w1b, b1a, b1b, w2a, w2b,
                                        b2a, b2b, w3a, w3b, b3a, b3b, ws);
    krone_main<<<NBLK, 256, 0, stream>>>(x, ws, out);
}

// Round 4
// 120.138 us; speedup vs baseline: 2.9846x; 2.9846x over previous
//
#include <hip/hip_runtime.h>
#include <hip/hip_bf16.h>

// ---------------------------------------------------------------------------
// KroneNet fused kernel v4 for MI355X (gfx950)
// out[i][j] = softmax_j( s_a[i] * t_j[i] )
// History: v2 (parallel paths, 62 us, 37 MB spill) > v3 (sequential paths,
// 294 us, 440 MB spill -- scheduler merged phase live-ranges). v4 = v2
// structure + v3's conflict-free padded W1 (verified 0 bank conflicts) +
// sched_barrier(0) fences to stop cross-phase live-range merging.
// ---------------------------------------------------------------------------

#define BTOT 262144
#define NBLK (BTOT / 256)   // 1024 blocks x 256 samples

typedef __attribute__((ext_vector_type(4))) float floatx4;
typedef __attribute__((ext_vector_type(8))) short bf16x8;
typedef __attribute__((ext_vector_type(4))) int  intx4;

// workspace / LDS layout (bytes)
#define OFF_W2  0          // 2 paths * 4 ksteps * 8 ntiles * 64 lanes * 16B = 65536
#define OFF_W1  65536      // 2 paths * 144 * float4 (128 + 16 pad slots)    = 4608
#define OFF_B2  70144      // 2 paths * 128 * float                          = 1024
#define OFF_W3A 71168      // 128 * float                                    = 512
#define OFF_W3B 71680      // 3 * 128 * float                                = 1536
#define OFF_B3  73216      // {b3a, b3b0, b3b1, b3b2}                        = 16
#define WS_TOTAL 73232

static __device__ __forceinline__ short f2bf(float f) {
    __hip_bfloat16 h = __float2bfloat16(f);
    return __builtin_bit_cast(short, h);
}

// pack two fp32 -> one dword of two bf16 (round-half-up), 3 VALU ops
static __device__ __forceinline__ int pack2bf(float lo, float hi) {
    unsigned a = __builtin_bit_cast(unsigned, lo) + 0x8000u;
    unsigned b = __builtin_bit_cast(unsigned, hi) + 0x8000u;
    return (int)__builtin_amdgcn_perm(b, a, 0x07060302u); // {b.hi16, a.hi16}
}

// compile-time-indexed 4-way select (NO dynamic register indexing)
#define SEL4(a0, a1, a2, a3, i) \
    ((i) == 0 ? (a0) : (i) == 1 ? (a1) : (i) == 2 ? (a2) : (a3))

static __device__ __forceinline__ float redcol(float v) {
    v += __shfl_xor(v, 1); v += __shfl_xor(v, 2);
    v += __shfl_xor(v, 4); v += __shfl_xor(v, 8);
    return v;
}

// W1 slot with bank-conflict padding: one extra float4 slot every 8 entries
static __device__ __forceinline__ int w1slot(int k) { return k + (k >> 3); }

// ---------------------------------------------------------------------------
// Pack kernel. W2 into MFMA B-fragment order: lane holds B[k=quad*8+j][n=col]
// for mfma_f32_16x16x32_bf16 (layout verified rounds 1-3).
// ---------------------------------------------------------------------------
__global__ void pack_kernel(const float* __restrict__ w1a, const float* __restrict__ w1b,
                            const float* __restrict__ b1a, const float* __restrict__ b1b,
                            const float* __restrict__ w2a, const float* __restrict__ w2b,
                            const float* __restrict__ b2a, const float* __restrict__ b2b,
                            const float* __restrict__ w3a, const float* __restrict__ w3b,
                            const float* __restrict__ b3a, const float* __restrict__ b3b,
                            unsigned char* __restrict__ ws) {
    const int b = blockIdx.x;
    const int tid = threadIdx.x;
    const int path = b >> 5;
    const int r = b & 31;
    const int s = r >> 3;
    const int t = r & 7;
    const float* w2 = path ? w2b : w2a;
    unsigned short* pk = (unsigned short*)(ws + OFF_W2 + path * 32768 + ((s * 8 + t) * 64) * 16);
    #pragma unroll
    for (int q = 0; q < 2; ++q) {
        int e = tid * 2 + q;
        int l = e >> 3, j = e & 7;
        int n = t * 16 + (l & 15);
        int k = s * 32 + ((l >> 4) * 8) + j;
        pk[e] = (unsigned short)f2bf(w2[n * 128 + k]);
    }
    if (b == 0) {
        {
            int pth = tid >> 7, k = tid & 127;
            const float* w1 = pth ? w1b : w1a;
            const float* b1 = pth ? b1b : b1a;
            ((float4*)(ws + OFF_W1))[pth * 144 + w1slot(k)] =
                make_float4(w1[2 * k], w1[2 * k + 1], b1[k], 0.f);
            ((float*)(ws + OFF_B2))[tid] = (pth ? b2b : b2a)[k];
        }
        if (tid < 128) ((float*)(ws + OFF_W3A))[tid] = w3a[tid];
        for (int i = tid; i < 384; i += 256) ((float*)(ws + OFF_W3B))[i] = w3b[i];
        if (tid == 0) {
            float* d = (float*)(ws + OFF_B3);
            d[0] = b3a[0]; d[1] = b3b[0]; d[2] = b3b[1]; d[3] = b3b[2];
        }
    }
}

// ---------------------------------------------------------------------------
// Main kernel: 1024 blocks x 256 threads (4 waves). Each wave computes BOTH
// paths (in parallel, v2-style) for its own 32 samples per chunk (2 chunks).
// Barrier-free main loop; per-wave LDS exchange pairs s_a with t_j.
// sched_barrier(0) fences keep the scheduler from merging phase live-ranges
// (v3 lesson: merged phases -> 440 MB scratch spill).
// ---------------------------------------------------------------------------
__global__ __launch_bounds__(256, 2)
void krone_main(const float* __restrict__ x, const unsigned char* __restrict__ ws,
                float* __restrict__ out) {
    __shared__ __align__(16) unsigned char smem[WS_TOTAL];
    __shared__ float4 sEx[4][32];

    const int tid = threadIdx.x;
    {
        const float4* src = (const float4*)ws;
        float4* dst = (float4*)smem;
        for (int i = tid; i < WS_TOTAL / 16; i += 256) dst[i] = src[i];
    }
    __syncthreads();

    const int lane = tid & 63;
    const int wave = tid >> 6;
    const int quad = lane >> 4;
    const int col  = lane & 15;

    const bf16x8* W2A = (const bf16x8*)(smem + OFF_W2);
    const bf16x8* W2B = (const bf16x8*)(smem + OFF_W2 + 32768);
    const float4* W1A = (const float4*)(smem + OFF_W1);
    const float4* W1B = W1A + 144;
    const float*  B2A = (const float*)(smem + OFF_B2);
    const float*  B2B = B2A + 128;
    const float*  W3A = (const float*)(smem + OFF_W3A);
    const float*  W3B = (const float*)(smem + OFF_W3B);
    const float*  B3  = (const float*)(smem + OFF_B3);
    const float2* xA  = (const float2*)x;
    const float2* xB  = xA + BTOT;

    #pragma unroll
    for (int c = 0; c < 2; ++c) {
        __builtin_amdgcn_sched_barrier(0);   // fence: no cross-chunk merging
        const int base = blockIdx.x * 256 + wave * 64 + c * 32;

        float2 xa[2], xb[2];
        #pragma unroll
        for (int mt = 0; mt < 2; ++mt) {
            xa[mt] = xA[base + mt * 16 + col];
            xb[mt] = xB[base + mt * 16 + col];
        }

        floatx4 accA[8][2], accB[8][2];
        #pragma unroll
        for (int t = 0; t < 8; ++t)
            #pragma unroll
            for (int mt = 0; mt < 2; ++mt) {
                accA[t][mt] = (floatx4){0.f, 0.f, 0.f, 0.f};
                accB[t][mt] = (floatx4){0.f, 0.f, 0.f, 0.f};
            }

        #pragma unroll
        for (int s = 0; s < 4; ++s) {
            // A-fragments on the fly: lane holds A[m=col][k=s*32+quad*8+j]
            intx4 afA[2], afB[2];
            const int bslot = s * 36 + quad * 9;   // padded W1 slot base
            #pragma unroll
            for (int j2 = 0; j2 < 4; ++j2) {
                float4 a0 = W1A[bslot + 2 * j2];
                float4 a1 = W1A[bslot + 2 * j2 + 1];
                float4 b0 = W1B[bslot + 2 * j2];
                float4 b1 = W1B[bslot + 2 * j2 + 1];
                #pragma unroll
                for (int mt = 0; mt < 2; ++mt) {
                    float ha0 = fmaxf(fmaf(xa[mt].x, a0.x, fmaf(xa[mt].y, a0.y, a0.z)), 0.f);
                    float ha1 = fmaxf(fmaf(xa[mt].x, a1.x, fmaf(xa[mt].y, a1.y, a1.z)), 0.f);
                    float hb0 = fmaxf(fmaf(xb[mt].x, b0.x, fmaf(xb[mt].y, b0.y, b0.z)), 0.f);
                    float hb1 = fmaxf(fmaf(xb[mt].x, b1.x, fmaf(xb[mt].y, b1.y, b1.z)), 0.f);
                    afA[mt][j2] = pack2bf(ha0, ha1);
                    afB[mt][j2] = pack2bf(hb0, hb1);
                }
            }
            #pragma unroll
            for (int t = 0; t < 8; ++t) {
                bf16x8 bfa = W2A[(s * 8 + t) * 64 + lane];
                bf16x8 bfb = W2B[(s * 8 + t) * 64 + lane];
                #pragma unroll
                for (int mt = 0; mt < 2; ++mt) {
                    accA[t][mt] = __builtin_amdgcn_mfma_f32_16x16x32_bf16(
                        __builtin_bit_cast(bf16x8, afA[mt]), bfa, accA[t][mt], 0, 0, 0);
                    accB[t][mt] = __builtin_amdgcn_mfma_f32_16x16x32_bf16(
                        __builtin_bit_cast(bf16x8, afB[mt]), bfb, accB[t][mt], 0, 0, 0);
                }
            }
        }
        __builtin_amdgcn_sched_barrier(0);   // fence: MFMA loop | epilogue

        // Epilogue. C layout: (t, mt, r) -> sample mt*16 + quad*4 + r, n = t*16+col.
        float pa[2][4]  = {};
        float pb0[2][4] = {}, pb1[2][4] = {}, pb2[2][4] = {};
        #pragma unroll
        for (int t = 0; t < 8; ++t) {
            int n = t * 16 + col;
            float b2a = B2A[n], w3a = W3A[n];
            float b2b = B2B[n];
            float w30 = W3B[n], w31 = W3B[128 + n], w32 = W3B[256 + n];
            #pragma unroll
            for (int mt = 0; mt < 2; ++mt)
                #pragma unroll
                for (int r = 0; r < 4; ++r) {
                    float ha = fmaxf(accA[t][mt][r] + b2a, 0.f);
                    pa[mt][r] = fmaf(w3a, ha, pa[mt][r]);
                    float hb = fmaxf(accB[t][mt][r] + b2b, 0.f);
                    pb0[mt][r] = fmaf(w30, hb, pb0[mt][r]);
                    pb1[mt][r] = fmaf(w31, hb, pb1[mt][r]);
                    pb2[mt][r] = fmaf(w32, hb, pb2[mt][r]);
                }
        }
        #pragma unroll
        for (int mt = 0; mt < 2; ++mt)
            #pragma unroll
            for (int r = 0; r < 4; ++r) {
                pa[mt][r]  = redcol(pa[mt][r]);
                pb0[mt][r] = redcol(pb0[mt][r]);
                pb1[mt][r] = redcol(pb1[mt][r]);
                pb2[mt][r] = redcol(pb2[mt][r]);
            }
        __builtin_amdgcn_sched_barrier(0);   // fence: reductions | exchange

        if (col < 4) {
            float b3a = B3[0], b30 = B3[1], b31 = B3[2], b32 = B3[3];
            #pragma unroll
            for (int mt = 0; mt < 2; ++mt) {
                int sl = mt * 16 + quad * 4 + col;
                float va = SEL4(pa[mt][0],  pa[mt][1],  pa[mt][2],  pa[mt][3],  col) + b3a;
                float v0 = SEL4(pb0[mt][0], pb0[mt][1], pb0[mt][2], pb0[mt][3], col) + b30;
                float v1 = SEL4(pb1[mt][0], pb1[mt][1], pb1[mt][2], pb1[mt][3], col) + b31;
                float v2 = SEL4(pb2[mt][0], pb2[mt][1], pb2[mt][2], pb2[mt][3], col) + b32;
                sEx[wave][sl] = make_float4(va, v0, v1, v2);
            }
        }
        // same-wave LDS RAW: ordered by lgkmcnt, no barrier needed
        if (lane < 32) {
            float4 v = sEx[wave][lane];
            float y0 = v.x * v.y, y1 = v.x * v.z, y2 = v.x * v.w;
            float m = fmaxf(y0, fmaxf(y1, y2));
            float e0 = __expf(y0 - m), e1 = __expf(y1 - m), e2 = __expf(y2 - m);
            float rs = 1.f / (e0 + e1 + e2);
            long o = (long)(base + lane) * 3;
            out[o]     = e0 * rs;
            out[o + 1] = e1 * rs;
            out[o + 2] = e2 * rs;
        }
        __builtin_amdgcn_sched_barrier(0);   // fence: chunk end
    }
}

extern "C" void kernel_launch(void* const* d_in, const int* in_sizes, int n_in,
                              void* d_out, int out_size, void* d_ws, size_t ws_size,
                              hipStream_t stream) {
    const float* x   = (const float*)d_in[0];
    const float* w1a = (const float*)d_in[1];
    const float* w1b = (const float*)d_in[2];
    const float* b1a = (const float*)d_in[3];
    const float* b1b = (const float*)d_in[4];
    const float* w2a = (const float*)d_in[5];
    const float* w2b = (const float*)d_in[6];
    const float* b2a = (const float*)d_in[7];
    const float* b2b = (const float*)d_in[8];
    const float* w3a = (const float*)d_in[9];
    const float* w3b = (const float*)d_in[10];
    const float* b3a = (const float*)d_in[11];
    const float* b3b = (const float*)d_in[12];
    unsigned char* ws = (unsigned char*)d_ws;
    float* out = (float*)d_out;

    pack_kernel<<<64, 256, 0, stream>>>(w1a, w1b, b1a, b1b, w2a, w2b,
                                        b2a, b2b, w3a, w3b, b3a, b3b, ws);
    krone_main<<<NBLK, 256, 0, stream>>>(x, ws, out);
}